// Round 10
// baseline (1730.397 us; speedup 1.0000x reference)
//
#include <hip/hip_runtime.h>

static constexpr int NB      = 16;
static constexpr int NPTS    = 4096;
static constexpr int NPOINTS = 1024;
static constexpr int NSAMP   = 32;
static constexpr int CIN0    = 67;   // 3 + 64
static constexpr int C0      = 64;
static constexpr int C1      = 64;
static constexpr int C2      = 128;
static constexpr int FB      = NB / 2;   // 8 paired-FPS blocks
static constexpr size_t MROWS = (size_t)NB * NPOINTS * NSAMP; // 524288
#define RAD2 0.16f
#define BN_EPS 0.001f

__device__ __forceinline__ float4 uld4(const float* __restrict__ p) {
    return *(const float4* __restrict__)p;
}

// bf16 RNE pack/unpack
__device__ __forceinline__ unsigned short f2bf(float f) {
    const unsigned u = __float_as_uint(f);
    return (unsigned short)((u + 0x7fffu + ((u >> 16) & 1u)) >> 16);
}
__device__ __forceinline__ float bf2f(unsigned short h) {
    return __uint_as_float((unsigned)h << 16);
}

// MFMA fragment types
typedef short bf16x8 __attribute__((ext_vector_type(8)));
typedef float f32x16 __attribute__((ext_vector_type(16)));
union UB { uint4 u; bf16x8 h; };

// ---- DPP helpers (VALU pipe) ----------------------------------------------
template<int CTRL>
__device__ __forceinline__ float dppf(float v) {
    return __int_as_float(__builtin_amdgcn_update_dpp(0, __float_as_int(v),
                                                      CTRL, 0xF, 0xF, false));
}
template<int CTRL>
__device__ __forceinline__ float dpps(float v) {
    return __int_as_float(__builtin_amdgcn_update_dpp(__float_as_int(v), __float_as_int(v),
                                                      CTRL, 0xF, 0xF, false));
}
__device__ __forceinline__ float dpp_sum64(float v) {
    v += dppf<0x111>(v); v += dppf<0x112>(v); v += dppf<0x114>(v); v += dppf<0x118>(v);
    v += dppf<0x142>(v); v += dppf<0x143>(v);
    return v;   // lane 63
}
__device__ __forceinline__ float dpp_psum16(float v) {
    v += dppf<0x111>(v); v += dppf<0x112>(v); v += dppf<0x114>(v); v += dppf<0x118>(v);
    return v;   // lanes 15,31,47,63
}
__device__ __forceinline__ float dpp_max32(float v) {
    v = fmaxf(v, dpps<0x111>(v)); v = fmaxf(v, dpps<0x112>(v));
    v = fmaxf(v, dpps<0x114>(v)); v = fmaxf(v, dpps<0x118>(v));
    v = fmaxf(v, dpps<0x142>(v));
    return v;   // lanes 31, 63
}
__device__ __forceinline__ float dpp_min32(float v) {
    v = fminf(v, dpps<0x111>(v)); v = fminf(v, dpps<0x112>(v));
    v = fminf(v, dpps<0x114>(v)); v = fminf(v, dpps<0x118>(v));
    v = fminf(v, dpps<0x142>(v));
    return v;   // lanes 31, 63
}
// u64-key argmax step: key = (f32bits(d) << 32) | (4095 - idx)
template<int CTRL>
__device__ __forceinline__ void kstep(unsigned long long& k) {
    const unsigned hi = (unsigned)(k >> 32);
    const unsigned lo = (unsigned)(k & 0xffffffffull);
    const unsigned ohi = (unsigned)__builtin_amdgcn_update_dpp((int)hi, (int)hi, CTRL, 0xF, 0xF, false);
    const unsigned olo = (unsigned)__builtin_amdgcn_update_dpp((int)lo, (int)lo, CTRL, 0xF, 0xF, false);
    const unsigned long long ok = ((unsigned long long)ohi << 32) | olo;
    if (ok > k) k = ok;
}

// ---------------------------------------------------------------------------
// Fused front kernel: blocks 0..7 = PAIRED FPS (two independent batches per
// block, interleaved so one instance's j-loop issue hides the other's
// barrier/LDS reduce latency; per-instance op order identical to r9 = exact).
// Block 8 = ws-zero + W2t transpose; blocks 9+ = preP (concurrent).
// ---------------------------------------------------------------------------
__global__ __launch_bounds__(512) void fps_kernel(const float* __restrict__ xyz,
                                                  float* __restrict__ out_newxyz,
                                                  float* __restrict__ wsz,
                                                  const float* __restrict__ points,
                                                  const float* __restrict__ W0,
                                                  float* __restrict__ P,
                                                  const float* __restrict__ W2,
                                                  unsigned short* __restrict__ W2t)
{
    if (blockIdx.x == FB) {
        for (int i = threadIdx.x; i < 1024; i += 512) wsz[i] = 0.f;
        if (W2t) {
            for (int i = threadIdx.x; i < C2 * C1; i += 512) {
                const int n = i >> 6, k = i & 63;
                W2t[i] = f2bf(W2[(size_t)k * C2 + n]);
            }
        }
        return;
    }
    if (blockIdx.x > FB) {
        // ---- preP: one row per thread ----
        const int r = (blockIdx.x - FB - 1) * 512 + threadIdx.x;   // 0..65535
        const float4* pr = (const float4*)(points + (size_t)r * 64);
        float x[64];
#pragma unroll
        for (int j = 0; j < 16; ++j) {
            const float4 v = pr[j];
            x[4*j+0] = v.x; x[4*j+1] = v.y; x[4*j+2] = v.z; x[4*j+3] = v.w;
        }
        float acc[64];
#pragma unroll
        for (int o = 0; o < 64; ++o) acc[o] = 0.f;
#pragma unroll 2
        for (int k = 0; k < 64; ++k) {
            const float xk = x[k];
#pragma unroll
            for (int oc = 0; oc < 16; ++oc) {
                const float4 w4 = uld4(W0 + (3 + k) * 64 + 4 * oc);
                acc[4*oc+0] = fmaf(xk, w4.x, acc[4*oc+0]);
                acc[4*oc+1] = fmaf(xk, w4.y, acc[4*oc+1]);
                acc[4*oc+2] = fmaf(xk, w4.z, acc[4*oc+2]);
                acc[4*oc+3] = fmaf(xk, w4.w, acc[4*oc+3]);
            }
        }
        float4* po = (float4*)(P + (size_t)r * 64);
#pragma unroll
        for (int oc = 0; oc < 16; ++oc)
            po[oc] = make_float4(acc[4*oc+0], acc[4*oc+1], acc[4*oc+2], acc[4*oc+3]);
        return;
    }

    // ---- paired FPS ----
    __shared__ float sxA[NPTS], syA[NPTS], szA[NPTS];
    __shared__ float sxB[NPTS], syB[NPTS], szB[NPTS];
    __shared__ int   sidxA[NPOINTS], sidxB[NPOINTS];
    __shared__ __align__(16) unsigned long long redkA[2][8], redkB[2][8];

    const int tid  = threadIdx.x;
    const int lane = tid & 63;
    const int wv   = tid >> 6;
    const int bA   = blockIdx.x * 2;
    const int bB   = bA + 1;

    const float* baseA = xyz + (size_t)bA * NPTS * 3;
    const float* baseB = xyz + (size_t)bB * NPTS * 3;
    for (int i = tid; i < NPTS; i += 512) {
        sxA[i] = baseA[i * 3 + 0]; syA[i] = baseA[i * 3 + 1]; szA[i] = baseA[i * 3 + 2];
        sxB[i] = baseB[i * 3 + 0]; syB[i] = baseB[i * 3 + 1]; szB[i] = baseB[i * 3 + 2];
    }
    __syncthreads();

    float pxA[8], pyA[8], pzA[8], ddA[8];
    float pxB[8], pyB[8], pzB[8], ddB[8];
#pragma unroll
    for (int j = 0; j < 8; ++j) {
        const int i = tid + j * 512;
        pxA[j] = sxA[i]; pyA[j] = syA[i]; pzA[j] = szA[i]; ddA[j] = 1e10f;
        pxB[j] = sxB[i]; pyB[j] = syB[i]; pzB[j] = szB[i]; ddB[j] = 1e10f;
    }

    int   farA = 0, farB = 0;
    float fxA = sxA[0], fyA = syA[0], fzA = szA[0];
    float fxB = sxB[0], fyB = syB[0], fzB = szB[0];

#pragma unroll 1
    for (int it = 0; it < NPOINTS; ++it) {
        if (tid == 0) { sidxA[it] = farA; sidxB[it] = farB; }

        // ---- instance A ----
        float bvA = -1.0f; int biA = 0;
#pragma unroll
        for (int j = 0; j < 8; ++j) {
            const float dx = __fsub_rn(pxA[j], fxA);
            const float dy = __fsub_rn(pyA[j], fyA);
            const float dz = __fsub_rn(pzA[j], fzA);
            const float d  = __fadd_rn(__fadd_rn(__fmul_rn(dx, dx), __fmul_rn(dy, dy)),
                                       __fmul_rn(dz, dz));
            ddA[j] = fminf(ddA[j], d);
            if (ddA[j] > bvA) { bvA = ddA[j]; biA = tid + j * 512; }
        }
        unsigned long long kA = ((unsigned long long)__float_as_uint(bvA) << 32)
                              | (unsigned)(4095 - biA);
        kstep<0x111>(kA); kstep<0x112>(kA); kstep<0x114>(kA);
        kstep<0x118>(kA); kstep<0x142>(kA); kstep<0x143>(kA);

        // ---- instance B ----
        float bvB = -1.0f; int biB = 0;
#pragma unroll
        for (int j = 0; j < 8; ++j) {
            const float dx = __fsub_rn(pxB[j], fxB);
            const float dy = __fsub_rn(pyB[j], fyB);
            const float dz = __fsub_rn(pzB[j], fzB);
            const float d  = __fadd_rn(__fadd_rn(__fmul_rn(dx, dx), __fmul_rn(dy, dy)),
                                       __fmul_rn(dz, dz));
            ddB[j] = fminf(ddB[j], d);
            if (ddB[j] > bvB) { bvB = ddB[j]; biB = tid + j * 512; }
        }
        unsigned long long kB = ((unsigned long long)__float_as_uint(bvB) << 32)
                              | (unsigned)(4095 - biB);
        kstep<0x111>(kB); kstep<0x112>(kB); kstep<0x114>(kB);
        kstep<0x118>(kB); kstep<0x142>(kB); kstep<0x143>(kB);

        const int pb = it & 1;
        if (lane == 63) { redkA[pb][wv] = kA; redkB[pb][wv] = kB; }
        __syncthreads();

        unsigned long long ckA = redkA[pb][0];
        unsigned long long ckB = redkB[pb][0];
#pragma unroll
        for (int w = 1; w < 8; ++w) {
            const unsigned long long oA = redkA[pb][w];
            const unsigned long long oB = redkB[pb][w];
            if (oA > ckA) ckA = oA;
            if (oB > ckB) ckB = oB;
        }
        const int ciA = 4095 - (int)(unsigned)(ckA & 0xffffffffull);
        const int ciB = 4095 - (int)(unsigned)(ckB & 0xffffffffull);
        farA = ciA; fxA = sxA[ciA]; fyA = syA[ciA]; fzA = szA[ciA];
        farB = ciB; fxB = sxB[ciB]; fyB = syB[ciB]; fzB = szB[ciB];
    }
    __syncthreads();
    for (int it = tid; it < NPOINTS; it += 512) {
        int ii = sidxA[it];
        float* o = out_newxyz + ((size_t)bA * NPOINTS + it) * 3;
        o[0] = sxA[ii]; o[1] = syA[ii]; o[2] = szA[ii];
        ii = sidxB[it];
        o = out_newxyz + ((size_t)bB * NPOINTS + it) * 3;
        o[0] = sxB[ii]; o[1] = syB[ii]; o[2] = szB[ii];
    }
}

// ---------------------------------------------------------------------------
// Ball query: one wave per center.
// ---------------------------------------------------------------------------
__global__ __launch_bounds__(256) void ball_kernel(const float* __restrict__ xyz,
                                                   const float* __restrict__ newxyz,
                                                   float* __restrict__ out_idx_f)
{
    __shared__ int sel[4][NSAMP];
    const int tid  = threadIdx.x;
    const int lane = tid & 63;
    const int widx = tid >> 6;
    const int w = blockIdx.x * 4 + widx;
    const int b = w >> 10;

    const float cx = newxyz[(size_t)w * 3 + 0];
    const float cy = newxyz[(size_t)w * 3 + 1];
    const float cz = newxyz[(size_t)w * 3 + 2];
    const float* base = xyz + (size_t)b * NPTS * 3;

    int total = 0;
    for (int c = 0; c < NPTS / 64 && total < NSAMP; ++c) {
        const int n = c * 64 + lane;
        const float dx = __fsub_rn(cx, base[n * 3 + 0]);
        const float dy = __fsub_rn(cy, base[n * 3 + 1]);
        const float dz = __fsub_rn(cz, base[n * 3 + 2]);
        const float d2 = __fadd_rn(__fadd_rn(__fmul_rn(dx, dx), __fmul_rn(dy, dy)),
                                   __fmul_rn(dz, dz));
        const bool pred = d2 < RAD2;
        const unsigned long long mask = __ballot(pred);
        if (pred) {
            const int pos = total + (int)__popcll(mask & ((1ull << lane) - 1ull));
            if (pos < NSAMP) sel[widx][pos] = n;
        }
        total += (int)__popcll(mask);
    }
    __syncthreads();
    if (lane < NSAMP) {
        const int first = sel[widx][0];
        const int v = (lane < total) ? sel[widx][lane] : first;
        out_idx_f[(size_t)w * NSAMP + lane] = (float)v;
    }
}

// ---------------------------------------------------------------------------
// Quad-slot stats (r7-proven): 16-lane psums, writers lanes 15/31/47/63.
// ---------------------------------------------------------------------------
__device__ __forceinline__ void stats4q(float a0, float a1, float a2, float a3,
                                        float* sa, bool wr)
{
    float q0 = a0*a0, q1 = a1*a1, q2 = a2*a2, q3 = a3*a3;
    a0 = dpp_psum16(a0); q0 = dpp_psum16(q0);
    a1 = dpp_psum16(a1); q1 = dpp_psum16(q1);
    a2 = dpp_psum16(a2); q2 = dpp_psum16(q2);
    a3 = dpp_psum16(a3); q3 = dpp_psum16(q3);
    if (wr) {
        sa[0] += a0; sa[1] += q0; sa[2] += a1; sa[3] += q1;
        sa[4] += a2; sa[5] += q2; sa[6] += a3; sa[7] += q3;
    }
}

// legacy full-wave stats (fallback tiers)
__device__ __forceinline__ void stats4(float a0, float a1, float a2, float a3,
                                       float* sa, int lane)
{
    float q0 = a0*a0, q1 = a1*a1, q2 = a2*a2, q3 = a3*a3;
    a0 = dpp_sum64(a0); q0 = dpp_sum64(q0);
    a1 = dpp_sum64(a1); q1 = dpp_sum64(q1);
    a2 = dpp_sum64(a2); q2 = dpp_sum64(q2);
    a3 = dpp_sum64(a3); q3 = dpp_sum64(q3);
    if (lane == 63) {
        sa[0] += a0; sa[1] += q0; sa[2] += a1; sa[3] += q1;
        sa[4] += a2; sa[5] += q2; sa[6] += a3; sa[7] += q3;
    }
}

// ---------------------------------------------------------------------------
// Shared body: gather + deduped layer 0 (pre-BN y0 into x1[64]).
// ---------------------------------------------------------------------------
__device__ __forceinline__ void layer0_dedup(
    const float* __restrict__ xyz, const float* __restrict__ P,
    const float* __restrict__ newxyz, const float* __restrict__ idxf,
    const float* __restrict__ W0, const float* __restrict__ b0,
    int r, float* x1)
{
    const int i  = (int)idxf[r];
    const int bb = r >> 15;
    const int pp = (r >> 5) & 1023;
    const float* pz = xyz + ((size_t)bb * NPTS + i) * 3;
    const float* nz = newxyz + ((size_t)bb * NPOINTS + pp) * 3;
    const float r0 = pz[0] - nz[0];
    const float r1 = pz[1] - nz[1];
    const float r2 = pz[2] - nz[2];
    const float4* prow = (const float4*)(P + ((size_t)bb * NPTS + i) * 64);
#pragma unroll
    for (int oc = 0; oc < 16; ++oc) {
        const float4 pv = prow[oc];
        const float4 bv = uld4(b0 + 4 * oc);
        const float4 wa = uld4(W0 + 0 * 64 + 4 * oc);
        const float4 wb = uld4(W0 + 1 * 64 + 4 * oc);
        const float4 wc = uld4(W0 + 2 * 64 + 4 * oc);
        x1[4*oc+0] = fmaf(r0, wa.x, fmaf(r1, wb.x, fmaf(r2, wc.x, bv.x + pv.x)));
        x1[4*oc+1] = fmaf(r0, wa.y, fmaf(r1, wb.y, fmaf(r2, wc.y, bv.y + pv.y)));
        x1[4*oc+2] = fmaf(r0, wa.z, fmaf(r1, wb.z, fmaf(r2, wc.z, bv.z + pv.z)));
        x1[4*oc+3] = fmaf(r0, wa.w, fmaf(r1, wb.w, fmaf(r2, wc.w, bv.w + pv.w)));
    }
}

// ---------------------------------------------------------------------------
// Pass 0 (r7-proven): stats of y0. Quad-slot psum16 stats.
// ---------------------------------------------------------------------------
__global__ __launch_bounds__(256, 4) void pass0_kernel(
    const float* __restrict__ xyz, const float* __restrict__ P,
    const float* __restrict__ newxyz, const float* __restrict__ idxf,
    const float* __restrict__ W0, const float* __restrict__ b0,
    float* __restrict__ gstats)
{
    __shared__ float sacc[16][2 * C0];
    const int tid  = threadIdx.x;
    const int lane = tid & 63;
    const int wv   = tid >> 6;
    const int slot = wv * 4 + (lane >> 4);
    const bool wr  = (lane & 15) == 15;

    for (int j = tid; j < 16 * 2 * C0; j += 256) (&sacc[0][0])[j] = 0.f;
    __syncthreads();

    const int r = blockIdx.x * 256 + tid;
    float x1[C0];
    layer0_dedup(xyz, P, newxyz, idxf, W0, b0, r, x1);

#pragma unroll
    for (int oc = 0; oc < 16; ++oc)
        stats4q(x1[4*oc+0], x1[4*oc+1], x1[4*oc+2], x1[4*oc+3], &sacc[slot][8*oc], wr);

    __syncthreads();
    for (int j = tid; j < 2 * C0; j += 256) {
        float s = 0.f;
#pragma unroll
        for (int q = 0; q < 16; ++q) s += sacc[q][j];
        atomicAdd(&gstats[j], s);
    }
}

// ---------------------------------------------------------------------------
// Pass 1 (r7-proven): bn0 from ss0, L1 matmul, stats y1, store y1 bf16.
// ---------------------------------------------------------------------------
__global__ __launch_bounds__(256, 3) void pass1Y_kernel(
    const float* __restrict__ xyz, const float* __restrict__ P,
    const float* __restrict__ newxyz, const float* __restrict__ idxf,
    const float* __restrict__ W0, const float* __restrict__ b0,
    const float* __restrict__ W1, const float* __restrict__ b1,
    const float* __restrict__ ss0,
    float* __restrict__ gstats, unsigned short* __restrict__ y1b)
{
    __shared__ float sacc[16][2 * C0];
    const int tid  = threadIdx.x;
    const int lane = tid & 63;
    const int wv   = tid >> 6;
    const int slot = wv * 4 + (lane >> 4);
    const bool wr  = (lane & 15) == 15;

    for (int j = tid; j < 16 * 2 * C0; j += 256) (&sacc[0][0])[j] = 0.f;
    __syncthreads();

    const int r = blockIdx.x * 256 + tid;
    float x1[C0];
    layer0_dedup(xyz, P, newxyz, idxf, W0, b0, r, x1);
#pragma unroll
    for (int o = 0; o < C0; ++o)
        x1[o] = fmaxf(0.f, fmaf(x1[o], ss0[o], ss0[64 + o]));

    float y1[C1];
#pragma unroll
    for (int o = 0; o < C1; o += 4) {
        const float4 bv = uld4(b1 + o);
        y1[o] = bv.x; y1[o+1] = bv.y; y1[o+2] = bv.z; y1[o+3] = bv.w;
    }
#pragma unroll 2
    for (int k = 0; k < C0; ++k) {
        const float xk = x1[k];
#pragma unroll
        for (int oc = 0; oc < 16; ++oc) {
            const float4 w4 = uld4(W1 + k * 64 + 4 * oc);
            y1[4*oc+0] = fmaf(xk, w4.x, y1[4*oc+0]);
            y1[4*oc+1] = fmaf(xk, w4.y, y1[4*oc+1]);
            y1[4*oc+2] = fmaf(xk, w4.z, y1[4*oc+2]);
            y1[4*oc+3] = fmaf(xk, w4.w, y1[4*oc+3]);
        }
    }

#pragma unroll
    for (int oc = 0; oc < 16; ++oc)
        stats4q(y1[4*oc+0], y1[4*oc+1], y1[4*oc+2], y1[4*oc+3], &sacc[slot][8*oc], wr);

    uint4* yo = (uint4*)(y1b + (size_t)r * 64);
#pragma unroll
    for (int gq = 0; gq < 8; ++gq) {
        union { unsigned short u[8]; uint4 v; } pk;
#pragma unroll
        for (int e = 0; e < 8; ++e) pk.u[e] = f2bf(y1[8*gq+e]);
        yo[gq] = pk.v;
    }

    __syncthreads();
    for (int j = tid; j < 2 * C0; j += 256) {
        float s = 0.f;
#pragma unroll
        for (int q = 0; q < 16; ++q) s += sacc[q][j];
        atomicAdd(&gstats[j], s);
    }
}

// ---------------------------------------------------------------------------
// Phase 2 via MFMA (r9-proven): 32x32x16 bf16, one wave = 32 rows x 128 ch.
// ---------------------------------------------------------------------------
__global__ __launch_bounds__(256, 3) void p2Ym_kernel(
    const unsigned short* __restrict__ y1b,
    const unsigned short* __restrict__ W2t,
    const float* __restrict__ b2,
    const float* __restrict__ ss1,
    float* __restrict__ gstats, float2* __restrict__ mnmx)
{
    __shared__ float  ssl[2 * C1];
    __shared__ float2 sacc[8][C2];
    __shared__ float2 mnacc[8][C2];

    const int tid  = threadIdx.x;
    const int lane = tid & 63;
    const int w    = tid >> 6;
    const int half = lane >> 5;
    const int col  = lane & 31;
    const int slot = w * 2 + half;

    for (int j = tid; j < 2 * C1; j += 256) ssl[j] = ss1[j];
    __syncthreads();

    const int r = blockIdx.x * 128 + w * 32 + col;   // A row (m = col)

    UB afrag[4];
#pragma unroll
    for (int t = 0; t < 4; ++t) {
        const int ko = t * 16 + half * 8;
        uint4 ua = *(const uint4*)(y1b + (size_t)r * 64 + ko);
        float scs[8], shs[8];
        *(float4*)&scs[0] = *(const float4*)&ssl[ko];
        *(float4*)&scs[4] = *(const float4*)&ssl[ko + 4];
        *(float4*)&shs[0] = *(const float4*)&ssl[64 + ko];
        *(float4*)&shs[4] = *(const float4*)&ssl[64 + ko + 4];
        const unsigned* ud = (const unsigned*)&ua;
        uint4 outw;
        unsigned* od = (unsigned*)&outw;
#pragma unroll
        for (int d = 0; d < 4; ++d) {
            const float flo = bf2f((unsigned short)(ud[d] & 0xffffu));
            const float fhi = bf2f((unsigned short)(ud[d] >> 16));
            const float vlo = fmaxf(0.f, fmaf(flo, scs[2*d],   shs[2*d]));
            const float vhi = fmaxf(0.f, fmaf(fhi, scs[2*d+1], shs[2*d+1]));
            od[d] = ((unsigned)f2bf(vhi) << 16) | (unsigned)f2bf(vlo);
        }
        afrag[t].u = outw;
    }

#pragma unroll
    for (int ct = 0; ct < 4; ++ct) {
        const float bias = b2[ct * 32 + col];
        f32x16 acc;
#pragma unroll
        for (int i = 0; i < 16; ++i) acc[i] = bias;
#pragma unroll
        for (int t = 0; t < 4; ++t) {
            UB bfrag;
            bfrag.u = *(const uint4*)(W2t + (size_t)(ct * 32 + col) * 64 + t * 16 + half * 8);
            acc = __builtin_amdgcn_mfma_f32_32x32x16_bf16(afrag[t].h, bfrag.h, acc, 0, 0, 0);
        }
        float s = 0.f, q = 0.f, mn = 3.4e38f, mx = -3.4e38f;
#pragma unroll
        for (int i = 0; i < 16; ++i) {
            const float v = acc[i];
            s += v; q = fmaf(v, v, q);
            mn = fminf(mn, v); mx = fmaxf(mx, v);
        }
        sacc[slot][ct * 32 + col]  = make_float2(s, q);
        mnacc[slot][ct * 32 + col] = make_float2(mn, mx);
    }

    __syncthreads();
    for (int j = tid; j < C2; j += 256) {
        float s = 0.f, q = 0.f;
#pragma unroll
        for (int v = 0; v < 8; ++v) { s += sacc[v][j].x; q += sacc[v][j].y; }
        atomicAdd(&gstats[2*j], s);
        atomicAdd(&gstats[2*j+1], q);
    }
    for (int j = tid; j < 4 * C2; j += 256) {
        const int wg = j >> 7, ch = j & 127;
        const float2 a = mnacc[2*wg][ch], bq = mnacc[2*wg+1][ch];
        mnmx[((size_t)blockIdx.x * 4 + wg) * C2 + ch] =
            make_float2(fminf(a.x, bq.x), fmaxf(a.y, bq.y));
    }
}

// ---------------------------------------------------------------------------
// Finalize: per-thread inline ss2; out = relu(sc>=0 ? sc*max+sh : sc*min+sh).
// ---------------------------------------------------------------------------
__global__ __launch_bounds__(256) void finY_kernel(const float2* __restrict__ mnmx,
                                                   const float* __restrict__ gs2,
                                                   const float* __restrict__ g2,
                                                   const float* __restrict__ be2,
                                                   float* __restrict__ out_np)
{
    const int t = blockIdx.x * 256 + threadIdx.x;
    const int g = t >> 7;
    const int o = t & 127;
    const float inv  = 1.0f / (float)MROWS;
    const float mean = gs2[2*o] * inv;
    const float var  = fmaxf(0.f, gs2[2*o+1] * inv - mean * mean);
    const float sc   = g2[o] / sqrtf(var + BN_EPS);
    const float sh   = fmaf(-mean, sc, be2[o]);
    const float2 mm  = mnmx[(size_t)g * C2 + o];
    const float y    = (sc >= 0.f) ? mm.y : mm.x;
    out_np[t] = fmaxf(0.f, fmaf(y, sc, sh));
}

// ---------------------------------------------------------------------------
// BN scale/shift kernel.
// ---------------------------------------------------------------------------
template<int C>
__global__ void ss_kernel(const float* __restrict__ gs, const float* __restrict__ g,
                          const float* __restrict__ be, float* __restrict__ ss)
{
    const int o = threadIdx.x;
    const float inv  = 1.0f / (float)MROWS;
    const float mean = gs[2*o] * inv;
    const float var  = fmaxf(0.f, gs[2*o+1] * inv - mean * mean);
    const float sc   = g[o] / sqrtf(var + BN_EPS);
    ss[o]     = sc;
    ss[C + o] = fmaf(-mean, sc, be[o]);
}

// ---------------------------------------------------------------------------
// Fallback P-path pass (P tier) — round-6 proven.
// ---------------------------------------------------------------------------
template<int PHASE>
__global__ __launch_bounds__(256, 2) void passP_kernel(
    const float* __restrict__ xyz, const float* __restrict__ P,
    const float* __restrict__ newxyz, const float* __restrict__ idxf,
    const float* __restrict__ W0, const float* __restrict__ b0,
    const float* __restrict__ W1, const float* __restrict__ b1,
    const float* __restrict__ W2, const float* __restrict__ b2,
    const float* __restrict__ ss0, const float* __restrict__ ss1,
    const float* __restrict__ ss2,
    float* __restrict__ gstats, float* __restrict__ out_np)
{
    constexpr int CS = (PHASE == 2) ? C2 : C0;
    __shared__ float sacc[4][2 * CS];

    const int tid  = threadIdx.x;
    const int lane = tid & 63;
    const int wv   = tid >> 6;

    if constexpr (PHASE <= 2) {
        for (int j = tid; j < 8 * CS; j += 256) (&sacc[0][0])[j] = 0.f;
        __syncthreads();
    }

    const int r = blockIdx.x * 256 + tid;
    float x1[C0];
    layer0_dedup(xyz, P, newxyz, idxf, W0, b0, r, x1);

    if constexpr (PHASE == 0) {
#pragma unroll
        for (int oc = 0; oc < 16; ++oc)
            stats4(x1[4*oc+0], x1[4*oc+1], x1[4*oc+2], x1[4*oc+3], &sacc[wv][8*oc], lane);
    } else {
#pragma unroll
        for (int o = 0; o < C0; ++o)
            x1[o] = fmaxf(0.f, fmaf(x1[o], ss0[o], ss0[64 + o]));

        float y1[C1];
#pragma unroll
        for (int o = 0; o < C1; o += 4) {
            const float4 bv = uld4(b1 + o);
            y1[o] = bv.x; y1[o+1] = bv.y; y1[o+2] = bv.z; y1[o+3] = bv.w;
        }
#pragma unroll 2
        for (int k = 0; k < C0; ++k) {
            const float xk = x1[k];
#pragma unroll
            for (int oc = 0; oc < 16; ++oc) {
                const float4 w4 = uld4(W1 + k * 64 + 4 * oc);
                y1[4*oc+0] = fmaf(xk, w4.x, y1[4*oc+0]);
                y1[4*oc+1] = fmaf(xk, w4.y, y1[4*oc+1]);
                y1[4*oc+2] = fmaf(xk, w4.z, y1[4*oc+2]);
                y1[4*oc+3] = fmaf(xk, w4.w, y1[4*oc+3]);
            }
        }

        if constexpr (PHASE == 1) {
#pragma unroll
            for (int oc = 0; oc < 16; ++oc)
                stats4(y1[4*oc+0], y1[4*oc+1], y1[4*oc+2], y1[4*oc+3], &sacc[wv][8*oc], lane);
        } else {
#pragma unroll
            for (int o = 0; o < C1; ++o)
                y1[o] = fmaxf(0.f, fmaf(y1[o], ss1[o], ss1[64 + o]));

            float a2[C2];
#pragma unroll
            for (int o = 0; o < C2; o += 4) {
                const float4 bv = uld4(b2 + o);
                a2[o] = bv.x; a2[o+1] = bv.y; a2[o+2] = bv.z; a2[o+3] = bv.w;
            }
#pragma unroll 2
            for (int k = 0; k < C1; ++k) {
                const float xk = y1[k];
#pragma unroll
                for (int o = 0; o < C2; o += 4) {
                    const float4 w4 = uld4(W2 + k * C2 + o);
                    a2[o+0] = fmaf(xk, w4.x, a2[o+0]);
                    a2[o+1] = fmaf(xk, w4.y, a2[o+1]);
                    a2[o+2] = fmaf(xk, w4.z, a2[o+2]);
                    a2[o+3] = fmaf(xk, w4.w, a2[o+3]);
                }
            }

            if constexpr (PHASE == 2) {
#pragma unroll
                for (int o = 0; o < C2; ++o) {
                    const float s = dpp_sum64(a2[o]);
                    const float q = dpp_sum64(a2[o] * a2[o]);
                    if (lane == 63) { sacc[wv][2*o] += s; sacc[wv][2*o+1] += q; }
                }
            } else {
                const int g = r >> 5;
#pragma unroll
                for (int o = 0; o < C2; ++o) {
                    float v = fmaxf(0.f, fmaf(a2[o], ss2[o], ss2[C2 + o]));
                    v = dpp_max32(v);
                    if (lane == 31 || lane == 63) out_np[(size_t)g * C2 + o] = v;
                }
            }
        }
    }

    if constexpr (PHASE <= 2) {
        __syncthreads();
        for (int j = tid; j < 2 * CS; j += 256)
            atomicAdd(&gstats[j], sacc[0][j] + sacc[1][j] + sacc[2][j] + sacc[3][j]);
    }
}

// ---------------------------------------------------------------------------
// Standalone preP (fallback P tier only).
// ---------------------------------------------------------------------------
__global__ __launch_bounds__(256) void preP_kernel(const float* __restrict__ points,
                                                   const float* __restrict__ W0,
                                                   float* __restrict__ P)
{
    const int r = blockIdx.x * 256 + threadIdx.x;
    const float4* pr = (const float4*)(points + (size_t)r * 64);
    float x[64];
#pragma unroll
    for (int j = 0; j < 16; ++j) {
        const float4 v = pr[j];
        x[4*j+0] = v.x; x[4*j+1] = v.y; x[4*j+2] = v.z; x[4*j+3] = v.w;
    }
    float acc[64];
#pragma unroll
    for (int o = 0; o < 64; ++o) acc[o] = 0.f;
#pragma unroll 2
    for (int k = 0; k < 64; ++k) {
        const float xk = x[k];
#pragma unroll
        for (int oc = 0; oc < 16; ++oc) {
            const float4 w4 = uld4(W0 + (3 + k) * 64 + 4 * oc);
            acc[4*oc+0] = fmaf(xk, w4.x, acc[4*oc+0]);
            acc[4*oc+1] = fmaf(xk, w4.y, acc[4*oc+1]);
            acc[4*oc+2] = fmaf(xk, w4.z, acc[4*oc+2]);
            acc[4*oc+3] = fmaf(xk, w4.w, acc[4*oc+3]);
        }
    }
    float4* po = (float4*)(P + (size_t)r * 64);
#pragma unroll
    for (int oc = 0; oc < 16; ++oc)
        po[oc] = make_float4(acc[4*oc+0], acc[4*oc+1], acc[4*oc+2], acc[4*oc+3]);
}

// ---------------------------------------------------------------------------
// Lowest-tier fallback (round-2 proven, ws < 16 MB).
// ---------------------------------------------------------------------------
template<int PHASE>
__global__ __launch_bounds__(128) void pass_kernel(
    const float* __restrict__ xyz, const float* __restrict__ points,
    const float* __restrict__ newxyz, const float* __restrict__ idxf,
    const float* __restrict__ W0, const float* __restrict__ b0,
    const float* __restrict__ W1, const float* __restrict__ b1,
    const float* __restrict__ W2, const float* __restrict__ b2,
    const float* __restrict__ ss0, const float* __restrict__ ss1,
    const float* __restrict__ ss2,
    float* __restrict__ gstats, float* __restrict__ out_np)
{
    constexpr int CS = (PHASE == 2) ? C2 : C0;
    __shared__ float xld[(PHASE >= 1) ? (64 * 128) : 1];
    __shared__ float sacc[2][2 * CS];

    const int tid  = threadIdx.x;
    const int lane = tid & 63;
    const int wv   = tid >> 6;

    if constexpr (PHASE <= 2) {
        for (int j = tid; j < 2 * 2 * CS; j += 128) (&sacc[0][0])[j] = 0.f;
        __syncthreads();
    }

    const int r  = blockIdx.x * 128 + tid;
    const int i  = (int)idxf[r];
    const int bb = r >> 15;
    const int pp = (r >> 5) & 1023;

    float x[CIN0];
    {
        const float* pz = xyz + ((size_t)bb * NPTS + i) * 3;
        const float* nz = newxyz + ((size_t)bb * NPOINTS + pp) * 3;
        x[0] = pz[0] - nz[0];
        x[1] = pz[1] - nz[1];
        x[2] = pz[2] - nz[2];
        const float4* p4 = (const float4*)(points + ((size_t)bb * NPTS + i) * 64);
#pragma unroll
        for (int j = 0; j < 16; ++j) {
            const float4 v = p4[j];
            x[3+4*j+0] = v.x; x[3+4*j+1] = v.y; x[3+4*j+2] = v.z; x[3+4*j+3] = v.w;
        }
    }

#pragma unroll 1
    for (int oc = 0; oc < 16; ++oc) {
        const float4 bv = uld4(b0 + 4*oc);
        float a0 = bv.x, a1 = bv.y, a2 = bv.z, a3 = bv.w;
#pragma unroll
        for (int k = 0; k < CIN0; ++k) {
            const float4 w4 = uld4(W0 + k*64 + 4*oc);
            a0 = fmaf(x[k], w4.x, a0); a1 = fmaf(x[k], w4.y, a1);
            a2 = fmaf(x[k], w4.z, a2); a3 = fmaf(x[k], w4.w, a3);
        }
        if constexpr (PHASE == 0) {
            stats4(a0, a1, a2, a3, &sacc[wv][8*oc], lane);
        } else {
            xld[(4*oc+0)*128 + tid] = fmaxf(0.f, fmaf(a0, ss0[4*oc+0], ss0[64+4*oc+0]));
            xld[(4*oc+1)*128 + tid] = fmaxf(0.f, fmaf(a1, ss0[4*oc+1], ss0[64+4*oc+1]));
            xld[(4*oc+2)*128 + tid] = fmaxf(0.f, fmaf(a2, ss0[4*oc+2], ss0[64+4*oc+2]));
            xld[(4*oc+3)*128 + tid] = fmaxf(0.f, fmaf(a3, ss0[4*oc+3], ss0[64+4*oc+3]));
        }
    }

    if constexpr (PHASE == 1) {
#pragma unroll 1
        for (int oc = 0; oc < 16; ++oc) {
            const float4 bv = uld4(b1 + 4*oc);
            float a0 = bv.x, a1 = bv.y, a2 = bv.z, a3 = bv.w;
#pragma unroll
            for (int k = 0; k < 64; ++k) {
                const float xk = xld[k*128 + tid];
                const float4 w4 = uld4(W1 + k*64 + 4*oc);
                a0 = fmaf(xk, w4.x, a0); a1 = fmaf(xk, w4.y, a1);
                a2 = fmaf(xk, w4.z, a2); a3 = fmaf(xk, w4.w, a3);
            }
            stats4(a0, a1, a2, a3, &sacc[wv][8*oc], lane);
        }
    }

    if constexpr (PHASE >= 2) {
        float acc2[C2];
#pragma unroll
        for (int o = 0; o < C2; o += 4) {
            const float4 bv = uld4(b2 + o);
            acc2[o] = bv.x; acc2[o+1] = bv.y; acc2[o+2] = bv.z; acc2[o+3] = bv.w;
        }
#pragma unroll 1
        for (int oc = 0; oc < 16; ++oc) {
            const float4 bv = uld4(b1 + 4*oc);
            float a0 = bv.x, a1 = bv.y, a2 = bv.z, a3 = bv.w;
#pragma unroll
            for (int k = 0; k < 64; ++k) {
                const float xk = xld[k*128 + tid];
                const float4 w4 = uld4(W1 + k*64 + 4*oc);
                a0 = fmaf(xk, w4.x, a0); a1 = fmaf(xk, w4.y, a1);
                a2 = fmaf(xk, w4.z, a2); a3 = fmaf(xk, w4.w, a3);
            }
            const float xc0 = fmaxf(0.f, fmaf(a0, ss1[4*oc+0], ss1[64+4*oc+0]));
            const float xc1 = fmaxf(0.f, fmaf(a1, ss1[4*oc+1], ss1[64+4*oc+1]));
            const float xc2 = fmaxf(0.f, fmaf(a2, ss1[4*oc+2], ss1[64+4*oc+2]));
            const float xc3 = fmaxf(0.f, fmaf(a3, ss1[4*oc+3], ss1[64+4*oc+3]));
#pragma unroll
            for (int o = 0; o < C2; o += 4) {
                const float4 wA = uld4(W2 + (4*oc+0)*C2 + o);
                const float4 wB = uld4(W2 + (4*oc+1)*C2 + o);
                const float4 wC = uld4(W2 + (4*oc+2)*C2 + o);
                const float4 wD = uld4(W2 + (4*oc+3)*C2 + o);
                acc2[o+0] = fmaf(xc0, wA.x, fmaf(xc1, wB.x, fmaf(xc2, wC.x, fmaf(xc3, wD.x, acc2[o+0]))));
                acc2[o+1] = fmaf(xc0, wA.y, fmaf(xc1, wB.y, fmaf(xc2, wC.y, fmaf(xc3, wD.y, acc2[o+1]))));
                acc2[o+2] = fmaf(xc0, wA.z, fmaf(xc1, wB.z, fmaf(xc2, wC.z, fmaf(xc3, wD.z, acc2[o+2]))));
                acc2[o+3] = fmaf(xc0, wA.w, fmaf(xc1, wB.w, fmaf(xc2, wC.w, fmaf(xc3, wD.w, acc2[o+3]))));
            }
        }

        if constexpr (PHASE == 2) {
#pragma unroll
            for (int o = 0; o < C2; ++o) {
                const float s = dpp_sum64(acc2[o]);
                const float q = dpp_sum64(acc2[o] * acc2[o]);
                if (lane == 63) { sacc[wv][2*o] += s; sacc[wv][2*o+1] += q; }
            }
        } else {
            const int g = r >> 5;
#pragma unroll
            for (int o = 0; o < C2; ++o) {
                float v = fmaxf(0.f, fmaf(acc2[o], ss2[o], ss2[C2+o]));
                v = dpp_max32(v);
                if (lane == 31 || lane == 63) out_np[(size_t)g * C2 + o] = v;
            }
        }
    }

    if constexpr (PHASE <= 2) {
        __syncthreads();
        for (int j = tid; j < 2 * CS; j += 128)
            atomicAdd(&gstats[j], sacc[0][j] + sacc[1][j]);
    }
}

extern "C" void kernel_launch(void* const* d_in, const int* in_sizes, int n_in,
                              void* d_out, int out_size, void* d_ws, size_t ws_size,
                              hipStream_t stream)
{
    (void)in_sizes; (void)n_in; (void)out_size;
    const float* xyz    = (const float*)d_in[0];
    const float* points = (const float*)d_in[1];
    const float* W0  = (const float*)d_in[2];
    const float* b0  = (const float*)d_in[3];
    const float* g0  = (const float*)d_in[4];
    const float* be0 = (const float*)d_in[5];
    const float* W1  = (const float*)d_in[6];
    const float* b1  = (const float*)d_in[7];
    const float* g1  = (const float*)d_in[8];
    const float* be1 = (const float*)d_in[9];
    const float* W2  = (const float*)d_in[10];
    const float* b2  = (const float*)d_in[11];
    const float* g2  = (const float*)d_in[12];
    const float* be2 = (const float*)d_in[13];

    float* out = (float*)d_out;
    float* out_newxyz = out;                                    // 16*1024*3
    float* out_newpts = out + (size_t)NB * NPOINTS * 3;         // 16*1024*128
    float* out_idx    = out_newpts + (size_t)NB * NPOINTS * C2; // 16*1024*32 (float idx)

    float* wsf = (float*)d_ws;
    float* gs0 = wsf + 0;    // 128
    float* gs1 = wsf + 128;  // 128
    float* gs2 = wsf + 256;  // 256
    float* ss0 = wsf + 512;  // 128
    float* ss1 = wsf + 640;  // 128
    float* ss2 = wsf + 768;  // 256
    const size_t PBYTES  = (size_t)NB * NPTS * C0 * 4;            // 16 MB
    const size_t MMBYTES = (size_t)NB * NPOINTS * 2 * C2 * 4;     // 16 MB
    const size_t YBYTES  = MROWS * C1 * 2;                        // 64 MB (bf16)
    const size_t TBYTES  = (size_t)C2 * C1 * 2;                   // 16 KB (W2t)
    float* P    = (float*)((char*)d_ws + 65536);
    float* mnmx = (float*)((char*)d_ws + 65536 + PBYTES);
    unsigned short* y1b = (unsigned short*)((char*)d_ws + 65536 + PBYTES + MMBYTES);
    unsigned short* W2t = (unsigned short*)((char*)d_ws + 65536 + PBYTES + MMBYTES + YBYTES);

    const bool haveP = ws_size >= (65536 + PBYTES);
    const bool haveY = ws_size >= (65536 + PBYTES + MMBYTES + YBYTES + TBYTES);

    const int frontGrid = FB + 1 + (haveP ? (NB * NPTS / 512) : 0);
    fps_kernel<<<frontGrid, 512, 0, stream>>>(xyz, out_newxyz, wsf, points, W0, P,
                                              W2, haveY ? W2t : nullptr);
    ball_kernel<<<(NB * NPOINTS) / 4, 256, 0, stream>>>(xyz, out_newxyz, out_idx);

    if (haveY) {
        const int grid = (int)(MROWS / 256);  // 2048
        pass0_kernel<<<grid, 256, 0, stream>>>(xyz, P, out_newxyz, out_idx,
                                               W0, b0, gs0);
        ss_kernel<C0><<<1, C0, 0, stream>>>(gs0, g0, be0, ss0);
        pass1Y_kernel<<<grid, 256, 0, stream>>>(xyz, P, out_newxyz, out_idx,
                                                W0, b0, W1, b1, ss0, gs1, y1b);
        ss_kernel<C1><<<1, C1, 0, stream>>>(gs1, g1, be1, ss1);
        p2Ym_kernel<<<(int)(MROWS / 128), 256, 0, stream>>>(y1b, W2t, b2, ss1,
                                                            gs2, (float2*)mnmx);
        finY_kernel<<<NB * NPOINTS * C2 / 256, 256, 0, stream>>>((const float2*)mnmx,
                                                                 gs2, g2, be2, out_newpts);
    } else if (haveP) {
        const int grid = (int)(MROWS / 256);  // 2048
        preP_kernel<<<NB * NPTS / 256, 256, 0, stream>>>(points, W0, P);
        passP_kernel<0><<<grid, 256, 0, stream>>>(xyz, P, out_newxyz, out_idx,
                                                  W0, b0, W1, b1, W2, b2,
                                                  ss0, ss1, ss2, gs0, nullptr);
        ss_kernel<C0><<<1, C0, 0, stream>>>(gs0, g0, be0, ss0);
        passP_kernel<1><<<grid, 256, 0, stream>>>(xyz, P, out_newxyz, out_idx,
                                                  W0, b0, W1, b1, W2, b2,
                                                  ss0, ss1, ss2, gs1, nullptr);
        ss_kernel<C1><<<1, C1, 0, stream>>>(gs1, g1, be1, ss1);
        passP_kernel<2><<<grid, 256, 0, stream>>>(xyz, P, out_newxyz, out_idx,
                                                  W0, b0, W1, b1, W2, b2,
                                                  ss0, ss1, ss2, gs2, nullptr);
        ss_kernel<C2><<<1, C2, 0, stream>>>(gs2, g2, be2, ss2);
        passP_kernel<3><<<grid, 256, 0, stream>>>(xyz, P, out_newxyz, out_idx,
                                                  W0, b0, W1, b1, W2, b2,
                                                  ss0, ss1, ss2, nullptr, out_newpts);
    } else {
        const int grid = (int)(MROWS / 128);  // 4096
        pass_kernel<0><<<grid, 128, 0, stream>>>(xyz, points, out_newxyz, out_idx,
                                                 W0, b0, W1, b1, W2, b2,
                                                 ss0, ss1, ss2, gs0, nullptr);
        ss_kernel<C0><<<1, C0, 0, stream>>>(gs0, g0, be0, ss0);
        pass_kernel<1><<<grid, 128, 0, stream>>>(xyz, points, out_newxyz, out_idx,
                                                 W0, b0, W1, b1, W2, b2,
                                                 ss0, ss1, ss2, gs1, nullptr);
        ss_kernel<C1><<<1, C1, 0, stream>>>(gs1, g1, be1, ss1);
        pass_kernel<2><<<grid, 128, 0, stream>>>(xyz, points, out_newxyz, out_idx,
                                                 W0, b0, W1, b1, W2, b2,
                                                 ss0, ss1, ss2, gs2, nullptr);
        ss_kernel<C2><<<1, C2, 0, stream>>>(gs2, g2, be2, ss2);
        pass_kernel<3><<<grid, 128, 0, stream>>>(xyz, points, out_newxyz, out_idx,
                                                 W0, b0, W1, b1, W2, b2,
                                                 ss0, ss1, ss2, nullptr, out_newpts);
    }
}

// Round 11
// 1196.917 us; speedup vs baseline: 1.4457x; 1.4457x over previous
//
#include <hip/hip_runtime.h>

static constexpr int NB      = 16;
static constexpr int NPTS    = 4096;
static constexpr int NPOINTS = 1024;
static constexpr int NSAMP   = 32;
static constexpr int CIN0    = 67;   // 3 + 64
static constexpr int C0      = 64;
static constexpr int C1      = 64;
static constexpr int C2      = 128;
static constexpr size_t MROWS = (size_t)NB * NPOINTS * NSAMP; // 524288
#define RAD2 0.16f
#define BN_EPS 0.001f

__device__ __forceinline__ float4 uld4(const float* __restrict__ p) {
    return *(const float4* __restrict__)p;
}

// bf16 RNE pack/unpack
__device__ __forceinline__ unsigned short f2bf(float f) {
    const unsigned u = __float_as_uint(f);
    return (unsigned short)((u + 0x7fffu + ((u >> 16) & 1u)) >> 16);
}
__device__ __forceinline__ float bf2f(unsigned short h) {
    return __uint_as_float((unsigned)h << 16);
}

// MFMA fragment types
typedef short bf16x8 __attribute__((ext_vector_type(8)));
typedef float f32x16 __attribute__((ext_vector_type(16)));
union UB { uint4 u; bf16x8 h; };

// ---- DPP helpers (VALU pipe) ----------------------------------------------
template<int CTRL>
__device__ __forceinline__ float dppf(float v) {
    return __int_as_float(__builtin_amdgcn_update_dpp(0, __float_as_int(v),
                                                      CTRL, 0xF, 0xF, false));
}
template<int CTRL>
__device__ __forceinline__ float dpps(float v) {
    return __int_as_float(__builtin_amdgcn_update_dpp(__float_as_int(v), __float_as_int(v),
                                                      CTRL, 0xF, 0xF, false));
}
__device__ __forceinline__ float dpp_sum64(float v) {
    v += dppf<0x111>(v); v += dppf<0x112>(v); v += dppf<0x114>(v); v += dppf<0x118>(v);
    v += dppf<0x142>(v); v += dppf<0x143>(v);
    return v;   // lane 63
}
__device__ __forceinline__ float dpp_psum16(float v) {
    v += dppf<0x111>(v); v += dppf<0x112>(v); v += dppf<0x114>(v); v += dppf<0x118>(v);
    return v;   // lanes 15,31,47,63
}
__device__ __forceinline__ float dpp_max32(float v) {
    v = fmaxf(v, dpps<0x111>(v)); v = fmaxf(v, dpps<0x112>(v));
    v = fmaxf(v, dpps<0x114>(v)); v = fmaxf(v, dpps<0x118>(v));
    v = fmaxf(v, dpps<0x142>(v));
    return v;   // lanes 31, 63
}
__device__ __forceinline__ float dpp_min32(float v) {
    v = fminf(v, dpps<0x111>(v)); v = fminf(v, dpps<0x112>(v));
    v = fminf(v, dpps<0x114>(v)); v = fminf(v, dpps<0x118>(v));
    v = fminf(v, dpps<0x142>(v));
    return v;   // lanes 31, 63
}
// u64-key argmax step: key = (f32bits(d) << 32) | (4095 - idx)
template<int CTRL>
__device__ __forceinline__ void kstep(unsigned long long& k) {
    const unsigned hi = (unsigned)(k >> 32);
    const unsigned lo = (unsigned)(k & 0xffffffffull);
    const unsigned ohi = (unsigned)__builtin_amdgcn_update_dpp((int)hi, (int)hi, CTRL, 0xF, 0xF, false);
    const unsigned olo = (unsigned)__builtin_amdgcn_update_dpp((int)lo, (int)lo, CTRL, 0xF, 0xF, false);
    const unsigned long long ok = ((unsigned long long)ohi << 32) | olo;
    if (ok > k) k = ok;
}

// ---------------------------------------------------------------------------
// Fused front kernel (r9-proven): blocks 0..15 = FPS; block 16 = ws-zero +
// W2t transpose; blocks 17+ = preP (concurrent on idle CUs).
// ---------------------------------------------------------------------------
__global__ __launch_bounds__(512) void fps_kernel(const float* __restrict__ xyz,
                                                  float* __restrict__ out_newxyz,
                                                  float* __restrict__ wsz,
                                                  const float* __restrict__ points,
                                                  const float* __restrict__ W0,
                                                  float* __restrict__ P,
                                                  const float* __restrict__ W2,
                                                  unsigned short* __restrict__ W2t)
{
    if (blockIdx.x == NB) {
        for (int i = threadIdx.x; i < 1024; i += 512) wsz[i] = 0.f;
        if (W2t) {
            for (int i = threadIdx.x; i < C2 * C1; i += 512) {
                const int n = i >> 6, k = i & 63;
                W2t[i] = f2bf(W2[(size_t)k * C2 + n]);
            }
        }
        return;
    }
    if (blockIdx.x > NB) {
        // ---- preP: one row per thread ----
        const int r = (blockIdx.x - NB - 1) * 512 + threadIdx.x;   // 0..65535
        const float4* pr = (const float4*)(points + (size_t)r * 64);
        float x[64];
#pragma unroll
        for (int j = 0; j < 16; ++j) {
            const float4 v = pr[j];
            x[4*j+0] = v.x; x[4*j+1] = v.y; x[4*j+2] = v.z; x[4*j+3] = v.w;
        }
        float acc[64];
#pragma unroll
        for (int o = 0; o < 64; ++o) acc[o] = 0.f;
#pragma unroll 2
        for (int k = 0; k < 64; ++k) {
            const float xk = x[k];
#pragma unroll
            for (int oc = 0; oc < 16; ++oc) {
                const float4 w4 = uld4(W0 + (3 + k) * 64 + 4 * oc);
                acc[4*oc+0] = fmaf(xk, w4.x, acc[4*oc+0]);
                acc[4*oc+1] = fmaf(xk, w4.y, acc[4*oc+1]);
                acc[4*oc+2] = fmaf(xk, w4.z, acc[4*oc+2]);
                acc[4*oc+3] = fmaf(xk, w4.w, acc[4*oc+3]);
            }
        }
        float4* po = (float4*)(P + (size_t)r * 64);
#pragma unroll
        for (int oc = 0; oc < 16; ++oc)
            po[oc] = make_float4(acc[4*oc+0], acc[4*oc+1], acc[4*oc+2], acc[4*oc+3]);
        return;
    }

    // ---- FPS (r9 single-batch form) ----
    __shared__ float sx[NPTS], sy[NPTS], sz[NPTS];
    __shared__ int   sidx[NPOINTS];
    __shared__ __align__(16) unsigned long long redk[2][8];

    const int b    = blockIdx.x;
    const int tid  = threadIdx.x;
    const int lane = tid & 63;
    const int wv   = tid >> 6;

    const float* base = xyz + (size_t)b * NPTS * 3;
    for (int i = tid; i < NPTS; i += 512) {
        sx[i] = base[i * 3 + 0];
        sy[i] = base[i * 3 + 1];
        sz[i] = base[i * 3 + 2];
    }
    __syncthreads();

    float px[8], py[8], pz[8], dd[8];
#pragma unroll
    for (int j = 0; j < 8; ++j) {
        const int i = tid + j * 512;
        px[j] = sx[i]; py[j] = sy[i]; pz[j] = sz[i];
        dd[j] = 1e10f;
    }

    int   far = 0;
    float fx = sx[0], fy = sy[0], fz = sz[0];
#pragma unroll 1
    for (int it = 0; it < NPOINTS; ++it) {
        if (tid == 0) sidx[it] = far;
        float bv = -1.0f; int bi = 0;
#pragma unroll
        for (int j = 0; j < 8; ++j) {
            const float dx = __fsub_rn(px[j], fx);
            const float dy = __fsub_rn(py[j], fy);
            const float dz = __fsub_rn(pz[j], fz);
            const float d  = __fadd_rn(__fadd_rn(__fmul_rn(dx, dx), __fmul_rn(dy, dy)),
                                       __fmul_rn(dz, dz));
            dd[j] = fminf(dd[j], d);
            if (dd[j] > bv) { bv = dd[j]; bi = tid + j * 512; }
        }
        unsigned long long k = ((unsigned long long)__float_as_uint(bv) << 32)
                             | (unsigned)(4095 - bi);
        kstep<0x111>(k);
        kstep<0x112>(k);
        kstep<0x114>(k);
        kstep<0x118>(k);
        kstep<0x142>(k);
        kstep<0x143>(k);

        const int pb = it & 1;
        if (lane == 63) redk[pb][wv] = k;
        __syncthreads();
        unsigned long long ck = redk[pb][0];
#pragma unroll
        for (int w = 1; w < 8; ++w) {
            const unsigned long long ok = redk[pb][w];
            if (ok > ck) ck = ok;
        }
        const int ci = 4095 - (int)(unsigned)(ck & 0xffffffffull);
        far = ci;
        fx = sx[ci]; fy = sy[ci]; fz = sz[ci];
    }
    __syncthreads();
    for (int it = tid; it < NPOINTS; it += 512) {
        const int ii = sidx[it];
        float* o = out_newxyz + ((size_t)b * NPOINTS + it) * 3;
        o[0] = sx[ii]; o[1] = sy[ii]; o[2] = sz[ii];
    }
}

// ---------------------------------------------------------------------------
// Quad-slot stats (r7-proven): 16-lane psums, writers lanes 15/31/47/63.
// ---------------------------------------------------------------------------
__device__ __forceinline__ void stats4q(float a0, float a1, float a2, float a3,
                                        float* sa, bool wr)
{
    float q0 = a0*a0, q1 = a1*a1, q2 = a2*a2, q3 = a3*a3;
    a0 = dpp_psum16(a0); q0 = dpp_psum16(q0);
    a1 = dpp_psum16(a1); q1 = dpp_psum16(q1);
    a2 = dpp_psum16(a2); q2 = dpp_psum16(q2);
    a3 = dpp_psum16(a3); q3 = dpp_psum16(q3);
    if (wr) {
        sa[0] += a0; sa[1] += q0; sa[2] += a1; sa[3] += q1;
        sa[4] += a2; sa[5] += q2; sa[6] += a3; sa[7] += q3;
    }
}

// legacy full-wave stats (fallback tiers)
__device__ __forceinline__ void stats4(float a0, float a1, float a2, float a3,
                                       float* sa, int lane)
{
    float q0 = a0*a0, q1 = a1*a1, q2 = a2*a2, q3 = a3*a3;
    a0 = dpp_sum64(a0); q0 = dpp_sum64(q0);
    a1 = dpp_sum64(a1); q1 = dpp_sum64(q1);
    a2 = dpp_sum64(a2); q2 = dpp_sum64(q2);
    a3 = dpp_sum64(a3); q3 = dpp_sum64(q3);
    if (lane == 63) {
        sa[0] += a0; sa[1] += q0; sa[2] += a1; sa[3] += q1;
        sa[4] += a2; sa[5] += q2; sa[6] += a3; sa[7] += q3;
    }
}

// ---------------------------------------------------------------------------
// L0 body with explicit sample index i (pre-BN y0 into x1[64]).
// ---------------------------------------------------------------------------
__device__ __forceinline__ void layer0_body(
    const float* __restrict__ xyz, const float* __restrict__ P,
    const float* __restrict__ newxyz,
    const float* __restrict__ W0, const float* __restrict__ b0,
    int i, int bb, int pp, float* x1)
{
    const float* pz = xyz + ((size_t)bb * NPTS + i) * 3;
    const float* nz = newxyz + ((size_t)bb * NPOINTS + pp) * 3;
    const float r0 = pz[0] - nz[0];
    const float r1 = pz[1] - nz[1];
    const float r2 = pz[2] - nz[2];
    const float4* prow = (const float4*)(P + ((size_t)bb * NPTS + i) * 64);
#pragma unroll
    for (int oc = 0; oc < 16; ++oc) {
        const float4 pv = prow[oc];
        const float4 bv = uld4(b0 + 4 * oc);
        const float4 wa = uld4(W0 + 0 * 64 + 4 * oc);
        const float4 wb = uld4(W0 + 1 * 64 + 4 * oc);
        const float4 wc = uld4(W0 + 2 * 64 + 4 * oc);
        x1[4*oc+0] = fmaf(r0, wa.x, fmaf(r1, wb.x, fmaf(r2, wc.x, bv.x + pv.x)));
        x1[4*oc+1] = fmaf(r0, wa.y, fmaf(r1, wb.y, fmaf(r2, wc.y, bv.y + pv.y)));
        x1[4*oc+2] = fmaf(r0, wa.z, fmaf(r1, wb.z, fmaf(r2, wc.z, bv.z + pv.z)));
        x1[4*oc+3] = fmaf(r0, wa.w, fmaf(r1, wb.w, fmaf(r2, wc.w, bv.w + pv.w)));
    }
}

__device__ __forceinline__ void layer0_dedup(
    const float* __restrict__ xyz, const float* __restrict__ P,
    const float* __restrict__ newxyz, const float* __restrict__ idxf,
    const float* __restrict__ W0, const float* __restrict__ b0,
    int r, float* x1)
{
    const int i  = (int)idxf[r];
    const int bb = r >> 15;
    const int pp = (r >> 5) & 1023;
    layer0_body(xyz, P, newxyz, W0, b0, i, bb, pp, x1);
}

// inline BN scale/shift into LDS (sc[C], sh[C]) from raw sums
template<int C>
__device__ __forceinline__ void bn_inline(const float* __restrict__ gs,
                                          const float* __restrict__ g,
                                          const float* __restrict__ be,
                                          float* ssl, int tid)
{
    if (tid < C) {
        const float inv  = 1.0f / (float)MROWS;
        const float mean = gs[2*tid] * inv;
        const float var  = fmaxf(0.f, gs[2*tid+1] * inv - mean * mean);
        const float sc   = g[tid] / sqrtf(var + BN_EPS);
        ssl[tid]     = sc;
        ssl[C + tid] = fmaf(-mean, sc, be[tid]);
    }
}

// ---------------------------------------------------------------------------
// Fused ball + pass0: 8 centers per 256-thread block (4 waves x 2 sequential
// centers; per-center op order identical to r9 ball -> exact idx). Phase B:
// thread t handles row blockIdx*256+t (same mapping as pass0), reads its
// sample from LDS sel, writes idx out, accumulates L0 stats.
// gstats layout here: interleaved {sum,q} pairs (gs0[2*j], gs0[2*j+1]).
// ---------------------------------------------------------------------------
__global__ __launch_bounds__(256, 4) void ballP0_kernel(
    const float* __restrict__ xyz, const float* __restrict__ P,
    const float* __restrict__ newxyz,
    const float* __restrict__ W0, const float* __restrict__ b0,
    float* __restrict__ gstats, float* __restrict__ out_idx_f)
{
    __shared__ int   sel[8][NSAMP];
    __shared__ int   stotal[8];
    __shared__ float sacc[16][2 * C0];

    const int tid  = threadIdx.x;
    const int lane = tid & 63;
    const int wv   = tid >> 6;

    for (int j = tid; j < 16 * 2 * C0; j += 256) (&sacc[0][0])[j] = 0.f;

    // ---- phase A: ball query, 2 centers per wave (sequential) ----
#pragma unroll 1
    for (int cc = 0; cc < 2; ++cc) {
        const int lc = wv * 2 + cc;                 // local center 0..7
        const int w  = blockIdx.x * 8 + lc;         // global center
        const int b  = w >> 10;
        const float cx = newxyz[(size_t)w * 3 + 0];
        const float cy = newxyz[(size_t)w * 3 + 1];
        const float cz = newxyz[(size_t)w * 3 + 2];
        const float* base = xyz + (size_t)b * NPTS * 3;

        int total = 0;
        for (int c = 0; c < NPTS / 64 && total < NSAMP; ++c) {
            const int n = c * 64 + lane;
            const float dx = __fsub_rn(cx, base[n * 3 + 0]);
            const float dy = __fsub_rn(cy, base[n * 3 + 1]);
            const float dz = __fsub_rn(cz, base[n * 3 + 2]);
            const float d2 = __fadd_rn(__fadd_rn(__fmul_rn(dx, dx), __fmul_rn(dy, dy)),
                                       __fmul_rn(dz, dz));
            const bool pred = d2 < RAD2;
            const unsigned long long mask = __ballot(pred);
            if (pred) {
                const int pos = total + (int)__popcll(mask & ((1ull << lane) - 1ull));
                if (pos < NSAMP) sel[lc][pos] = n;
            }
            total += (int)__popcll(mask);
        }
        if (lane == 0) stotal[lc] = (total < NSAMP) ? total : NSAMP;
    }
    __syncthreads();

    // ---- phase B: row = blockIdx*256 + tid ----
    const int r  = blockIdx.x * 256 + tid;
    const int ci = tid >> 5;       // local center
    const int s  = tid & 31;
    const int tt = stotal[ci];
    const int n  = (s < tt) ? sel[ci][s] : sel[ci][0];
    out_idx_f[r] = (float)n;

    const int bb = r >> 15;
    const int pp = (r >> 5) & 1023;
    float x1[C0];
    layer0_body(xyz, P, newxyz, W0, b0, n, bb, pp, x1);

    const int slot = wv * 4 + (lane >> 4);
    const bool wr  = (lane & 15) == 15;
#pragma unroll
    for (int oc = 0; oc < 16; ++oc)
        stats4q(x1[4*oc+0], x1[4*oc+1], x1[4*oc+2], x1[4*oc+3], &sacc[slot][8*oc], wr);

    __syncthreads();
    for (int j = tid; j < 2 * C0; j += 256) {
        float ssum = 0.f;
#pragma unroll
        for (int q = 0; q < 16; ++q) ssum += sacc[q][j];
        atomicAdd(&gstats[j], ssum);
    }
}

// ---------------------------------------------------------------------------
// Pass 1: inline bn0 from gs0, L1 matmul, stats y1, store y1 bf16.
// ---------------------------------------------------------------------------
__global__ __launch_bounds__(256, 3) void pass1Y_kernel(
    const float* __restrict__ xyz, const float* __restrict__ P,
    const float* __restrict__ newxyz, const float* __restrict__ idxf,
    const float* __restrict__ W0, const float* __restrict__ b0,
    const float* __restrict__ W1, const float* __restrict__ b1,
    const float* __restrict__ gs0, const float* __restrict__ g0,
    const float* __restrict__ be0,
    float* __restrict__ gstats, unsigned short* __restrict__ y1b)
{
    __shared__ float sacc[16][2 * C0];
    __shared__ float ssl[2 * C0];
    const int tid  = threadIdx.x;
    const int lane = tid & 63;
    const int wv   = tid >> 6;
    const int slot = wv * 4 + (lane >> 4);
    const bool wr  = (lane & 15) == 15;

    for (int j = tid; j < 16 * 2 * C0; j += 256) (&sacc[0][0])[j] = 0.f;
    bn_inline<C0>(gs0, g0, be0, ssl, tid);
    __syncthreads();

    const int r = blockIdx.x * 256 + tid;
    float x1[C0];
    layer0_dedup(xyz, P, newxyz, idxf, W0, b0, r, x1);
#pragma unroll
    for (int o = 0; o < C0; ++o)
        x1[o] = fmaxf(0.f, fmaf(x1[o], ssl[o], ssl[64 + o]));

    float y1[C1];
#pragma unroll
    for (int o = 0; o < C1; o += 4) {
        const float4 bv = uld4(b1 + o);
        y1[o] = bv.x; y1[o+1] = bv.y; y1[o+2] = bv.z; y1[o+3] = bv.w;
    }
#pragma unroll 2
    for (int k = 0; k < C0; ++k) {
        const float xk = x1[k];
#pragma unroll
        for (int oc = 0; oc < 16; ++oc) {
            const float4 w4 = uld4(W1 + k * 64 + 4 * oc);
            y1[4*oc+0] = fmaf(xk, w4.x, y1[4*oc+0]);
            y1[4*oc+1] = fmaf(xk, w4.y, y1[4*oc+1]);
            y1[4*oc+2] = fmaf(xk, w4.z, y1[4*oc+2]);
            y1[4*oc+3] = fmaf(xk, w4.w, y1[4*oc+3]);
        }
    }

#pragma unroll
    for (int oc = 0; oc < 16; ++oc)
        stats4q(y1[4*oc+0], y1[4*oc+1], y1[4*oc+2], y1[4*oc+3], &sacc[slot][8*oc], wr);

    uint4* yo = (uint4*)(y1b + (size_t)r * 64);
#pragma unroll
    for (int gq = 0; gq < 8; ++gq) {
        union { unsigned short u[8]; uint4 v; } pk;
#pragma unroll
        for (int e = 0; e < 8; ++e) pk.u[e] = f2bf(y1[8*gq+e]);
        yo[gq] = pk.v;
    }

    __syncthreads();
    for (int j = tid; j < 2 * C0; j += 256) {
        float s = 0.f;
#pragma unroll
        for (int q = 0; q < 16; ++q) s += sacc[q][j];
        atomicAdd(&gstats[j], s);
    }
}

// ---------------------------------------------------------------------------
// Phase 2 via MFMA (r9-proven) with inline bn1 from gs1.
// ---------------------------------------------------------------------------
__global__ __launch_bounds__(256, 3) void p2Ym_kernel(
    const unsigned short* __restrict__ y1b,
    const unsigned short* __restrict__ W2t,
    const float* __restrict__ b2,
    const float* __restrict__ gs1, const float* __restrict__ g1,
    const float* __restrict__ be1,
    float* __restrict__ gstats, float2* __restrict__ mnmx)
{
    __shared__ float  ssl[2 * C1];
    __shared__ float2 sacc[8][C2];
    __shared__ float2 mnacc[8][C2];

    const int tid  = threadIdx.x;
    const int lane = tid & 63;
    const int w    = tid >> 6;
    const int half = lane >> 5;
    const int col  = lane & 31;
    const int slot = w * 2 + half;

    bn_inline<C1>(gs1, g1, be1, ssl, tid);
    __syncthreads();

    const int r = blockIdx.x * 128 + w * 32 + col;   // A row (m = col)

    UB afrag[4];
#pragma unroll
    for (int t = 0; t < 4; ++t) {
        const int ko = t * 16 + half * 8;
        uint4 ua = *(const uint4*)(y1b + (size_t)r * 64 + ko);
        float scs[8], shs[8];
        *(float4*)&scs[0] = *(const float4*)&ssl[ko];
        *(float4*)&scs[4] = *(const float4*)&ssl[ko + 4];
        *(float4*)&shs[0] = *(const float4*)&ssl[64 + ko];
        *(float4*)&shs[4] = *(const float4*)&ssl[64 + ko + 4];
        const unsigned* ud = (const unsigned*)&ua;
        uint4 outw;
        unsigned* od = (unsigned*)&outw;
#pragma unroll
        for (int d = 0; d < 4; ++d) {
            const float flo = bf2f((unsigned short)(ud[d] & 0xffffu));
            const float fhi = bf2f((unsigned short)(ud[d] >> 16));
            const float vlo = fmaxf(0.f, fmaf(flo, scs[2*d],   shs[2*d]));
            const float vhi = fmaxf(0.f, fmaf(fhi, scs[2*d+1], shs[2*d+1]));
            od[d] = ((unsigned)f2bf(vhi) << 16) | (unsigned)f2bf(vlo);
        }
        afrag[t].u = outw;
    }

#pragma unroll
    for (int ct = 0; ct < 4; ++ct) {
        const float bias = b2[ct * 32 + col];
        f32x16 acc;
#pragma unroll
        for (int i = 0; i < 16; ++i) acc[i] = bias;
#pragma unroll
        for (int t = 0; t < 4; ++t) {
            UB bfrag;
            bfrag.u = *(const uint4*)(W2t + (size_t)(ct * 32 + col) * 64 + t * 16 + half * 8);
            acc = __builtin_amdgcn_mfma_f32_32x32x16_bf16(afrag[t].h, bfrag.h, acc, 0, 0, 0);
        }
        float s = 0.f, q = 0.f, mn = 3.4e38f, mx = -3.4e38f;
#pragma unroll
        for (int i = 0; i < 16; ++i) {
            const float v = acc[i];
            s += v; q = fmaf(v, v, q);
            mn = fminf(mn, v); mx = fmaxf(mx, v);
        }
        sacc[slot][ct * 32 + col]  = make_float2(s, q);
        mnacc[slot][ct * 32 + col] = make_float2(mn, mx);
    }

    __syncthreads();
    for (int j = tid; j < C2; j += 256) {
        float s = 0.f, q = 0.f;
#pragma unroll
        for (int v = 0; v < 8; ++v) { s += sacc[v][j].x; q += sacc[v][j].y; }
        atomicAdd(&gstats[2*j], s);
        atomicAdd(&gstats[2*j+1], q);
    }
    for (int j = tid; j < 4 * C2; j += 256) {
        const int wg = j >> 7, ch = j & 127;
        const float2 a = mnacc[2*wg][ch], bq = mnacc[2*wg+1][ch];
        mnmx[((size_t)blockIdx.x * 4 + wg) * C2 + ch] =
            make_float2(fminf(a.x, bq.x), fmaxf(a.y, bq.y));
    }
}

// ---------------------------------------------------------------------------
// Finalize: per-thread inline ss2; out = relu(sc>=0 ? sc*max+sh : sc*min+sh).
// ---------------------------------------------------------------------------
__global__ __launch_bounds__(256) void finY_kernel(const float2* __restrict__ mnmx,
                                                   const float* __restrict__ gs2,
                                                   const float* __restrict__ g2,
                                                   const float* __restrict__ be2,
                                                   float* __restrict__ out_np)
{
    const int t = blockIdx.x * 256 + threadIdx.x;
    const int g = t >> 7;
    const int o = t & 127;
    const float inv  = 1.0f / (float)MROWS;
    const float mean = gs2[2*o] * inv;
    const float var  = fmaxf(0.f, gs2[2*o+1] * inv - mean * mean);
    const float sc   = g2[o] / sqrtf(var + BN_EPS);
    const float sh   = fmaf(-mean, sc, be2[o]);
    const float2 mm  = mnmx[(size_t)g * C2 + o];
    const float y    = (sc >= 0.f) ? mm.y : mm.x;
    out_np[t] = fmaxf(0.f, fmaf(y, sc, sh));
}

// ---------------------------------------------------------------------------
// Standalone ball (fallback tiers).
// ---------------------------------------------------------------------------
__global__ __launch_bounds__(256) void ball_kernel(const float* __restrict__ xyz,
                                                   const float* __restrict__ newxyz,
                                                   float* __restrict__ out_idx_f)
{
    __shared__ int sel[4][NSAMP];
    const int tid  = threadIdx.x;
    const int lane = tid & 63;
    const int widx = tid >> 6;
    const int w = blockIdx.x * 4 + widx;
    const int b = w >> 10;

    const float cx = newxyz[(size_t)w * 3 + 0];
    const float cy = newxyz[(size_t)w * 3 + 1];
    const float cz = newxyz[(size_t)w * 3 + 2];
    const float* base = xyz + (size_t)b * NPTS * 3;

    int total = 0;
    for (int c = 0; c < NPTS / 64 && total < NSAMP; ++c) {
        const int n = c * 64 + lane;
        const float dx = __fsub_rn(cx, base[n * 3 + 0]);
        const float dy = __fsub_rn(cy, base[n * 3 + 1]);
        const float dz = __fsub_rn(cz, base[n * 3 + 2]);
        const float d2 = __fadd_rn(__fadd_rn(__fmul_rn(dx, dx), __fmul_rn(dy, dy)),
                                   __fmul_rn(dz, dz));
        const bool pred = d2 < RAD2;
        const unsigned long long mask = __ballot(pred);
        if (pred) {
            const int pos = total + (int)__popcll(mask & ((1ull << lane) - 1ull));
            if (pos < NSAMP) sel[widx][pos] = n;
        }
        total += (int)__popcll(mask);
    }
    __syncthreads();
    if (lane < NSAMP) {
        const int first = sel[widx][0];
        const int v = (lane < total) ? sel[widx][lane] : first;
        out_idx_f[(size_t)w * NSAMP + lane] = (float)v;
    }
}

// ---------------------------------------------------------------------------
// BN scale/shift kernel (fallback tiers).
// ---------------------------------------------------------------------------
template<int C>
__global__ void ss_kernel(const float* __restrict__ gs, const float* __restrict__ g,
                          const float* __restrict__ be, float* __restrict__ ss)
{
    const int o = threadIdx.x;
    const float inv  = 1.0f / (float)MROWS;
    const float mean = gs[2*o] * inv;
    const float var  = fmaxf(0.f, gs[2*o+1] * inv - mean * mean);
    const float sc   = g[o] / sqrtf(var + BN_EPS);
    ss[o]     = sc;
    ss[C + o] = fmaf(-mean, sc, be[o]);
}

// ---------------------------------------------------------------------------
// Fallback P-path pass (P tier) — round-6 proven.
// ---------------------------------------------------------------------------
template<int PHASE>
__global__ __launch_bounds__(256, 2) void passP_kernel(
    const float* __restrict__ xyz, const float* __restrict__ P,
    const float* __restrict__ newxyz, const float* __restrict__ idxf,
    const float* __restrict__ W0, const float* __restrict__ b0,
    const float* __restrict__ W1, const float* __restrict__ b1,
    const float* __restrict__ W2, const float* __restrict__ b2,
    const float* __restrict__ ss0, const float* __restrict__ ss1,
    const float* __restrict__ ss2,
    float* __restrict__ gstats, float* __restrict__ out_np)
{
    constexpr int CS = (PHASE == 2) ? C2 : C0;
    __shared__ float sacc[4][2 * CS];

    const int tid  = threadIdx.x;
    const int lane = tid & 63;
    const int wv   = tid >> 6;

    if constexpr (PHASE <= 2) {
        for (int j = tid; j < 8 * CS; j += 256) (&sacc[0][0])[j] = 0.f;
        __syncthreads();
    }

    const int r = blockIdx.x * 256 + tid;
    float x1[C0];
    layer0_dedup(xyz, P, newxyz, idxf, W0, b0, r, x1);

    if constexpr (PHASE == 0) {
#pragma unroll
        for (int oc = 0; oc < 16; ++oc)
            stats4(x1[4*oc+0], x1[4*oc+1], x1[4*oc+2], x1[4*oc+3], &sacc[wv][8*oc], lane);
    } else {
#pragma unroll
        for (int o = 0; o < C0; ++o)
            x1[o] = fmaxf(0.f, fmaf(x1[o], ss0[o], ss0[64 + o]));

        float y1[C1];
#pragma unroll
        for (int o = 0; o < C1; o += 4) {
            const float4 bv = uld4(b1 + o);
            y1[o] = bv.x; y1[o+1] = bv.y; y1[o+2] = bv.z; y1[o+3] = bv.w;
        }
#pragma unroll 2
        for (int k = 0; k < C0; ++k) {
            const float xk = x1[k];
#pragma unroll
            for (int oc = 0; oc < 16; ++oc) {
                const float4 w4 = uld4(W1 + k * 64 + 4 * oc);
                y1[4*oc+0] = fmaf(xk, w4.x, y1[4*oc+0]);
                y1[4*oc+1] = fmaf(xk, w4.y, y1[4*oc+1]);
                y1[4*oc+2] = fmaf(xk, w4.z, y1[4*oc+2]);
                y1[4*oc+3] = fmaf(xk, w4.w, y1[4*oc+3]);
            }
        }

        if constexpr (PHASE == 1) {
#pragma unroll
            for (int oc = 0; oc < 16; ++oc)
                stats4(y1[4*oc+0], y1[4*oc+1], y1[4*oc+2], y1[4*oc+3], &sacc[wv][8*oc], lane);
        } else {
#pragma unroll
            for (int o = 0; o < C1; ++o)
                y1[o] = fmaxf(0.f, fmaf(y1[o], ss1[o], ss1[64 + o]));

            float a2[C2];
#pragma unroll
            for (int o = 0; o < C2; o += 4) {
                const float4 bv = uld4(b2 + o);
                a2[o] = bv.x; a2[o+1] = bv.y; a2[o+2] = bv.z; a2[o+3] = bv.w;
            }
#pragma unroll 2
            for (int k = 0; k < C1; ++k) {
                const float xk = y1[k];
#pragma unroll
                for (int o = 0; o < C2; o += 4) {
                    const float4 w4 = uld4(W2 + k * C2 + o);
                    a2[o+0] = fmaf(xk, w4.x, a2[o+0]);
                    a2[o+1] = fmaf(xk, w4.y, a2[o+1]);
                    a2[o+2] = fmaf(xk, w4.z, a2[o+2]);
                    a2[o+3] = fmaf(xk, w4.w, a2[o+3]);
                }
            }

            if constexpr (PHASE == 2) {
#pragma unroll
                for (int o = 0; o < C2; ++o) {
                    const float s = dpp_sum64(a2[o]);
                    const float q = dpp_sum64(a2[o] * a2[o]);
                    if (lane == 63) { sacc[wv][2*o] += s; sacc[wv][2*o+1] += q; }
                }
            } else {
                const int g = r >> 5;
#pragma unroll
                for (int o = 0; o < C2; ++o) {
                    float v = fmaxf(0.f, fmaf(a2[o], ss2[o], ss2[C2 + o]));
                    v = dpp_max32(v);
                    if (lane == 31 || lane == 63) out_np[(size_t)g * C2 + o] = v;
                }
            }
        }
    }

    if constexpr (PHASE <= 2) {
        __syncthreads();
        for (int j = tid; j < 2 * CS; j += 256)
            atomicAdd(&gstats[j], sacc[0][j] + sacc[1][j] + sacc[2][j] + sacc[3][j]);
    }
}

// ---------------------------------------------------------------------------
// Standalone preP (fallback P tier only).
// ---------------------------------------------------------------------------
__global__ __launch_bounds__(256) void preP_kernel(const float* __restrict__ points,
                                                   const float* __restrict__ W0,
                                                   float* __restrict__ P)
{
    const int r = blockIdx.x * 256 + threadIdx.x;
    const float4* pr = (const float4*)(points + (size_t)r * 64);
    float x[64];
#pragma unroll
    for (int j = 0; j < 16; ++j) {
        const float4 v = pr[j];
        x[4*j+0] = v.x; x[4*j+1] = v.y; x[4*j+2] = v.z; x[4*j+3] = v.w;
    }
    float acc[64];
#pragma unroll
    for (int o = 0; o < 64; ++o) acc[o] = 0.f;
#pragma unroll 2
    for (int k = 0; k < 64; ++k) {
        const float xk = x[k];
#pragma unroll
        for (int oc = 0; oc < 16; ++oc) {
            const float4 w4 = uld4(W0 + (3 + k) * 64 + 4 * oc);
            acc[4*oc+0] = fmaf(xk, w4.x, acc[4*oc+0]);
            acc[4*oc+1] = fmaf(xk, w4.y, acc[4*oc+1]);
            acc[4*oc+2] = fmaf(xk, w4.z, acc[4*oc+2]);
            acc[4*oc+3] = fmaf(xk, w4.w, acc[4*oc+3]);
        }
    }
    float4* po = (float4*)(P + (size_t)r * 64);
#pragma unroll
    for (int oc = 0; oc < 16; ++oc)
        po[oc] = make_float4(acc[4*oc+0], acc[4*oc+1], acc[4*oc+2], acc[4*oc+3]);
}

// ---------------------------------------------------------------------------
// Lowest-tier fallback (round-2 proven, ws < 16 MB).
// ---------------------------------------------------------------------------
template<int PHASE>
__global__ __launch_bounds__(128) void pass_kernel(
    const float* __restrict__ xyz, const float* __restrict__ points,
    const float* __restrict__ newxyz, const float* __restrict__ idxf,
    const float* __restrict__ W0, const float* __restrict__ b0,
    const float* __restrict__ W1, const float* __restrict__ b1,
    const float* __restrict__ W2, const float* __restrict__ b2,
    const float* __restrict__ ss0, const float* __restrict__ ss1,
    const float* __restrict__ ss2,
    float* __restrict__ gstats, float* __restrict__ out_np)
{
    constexpr int CS = (PHASE == 2) ? C2 : C0;
    __shared__ float xld[(PHASE >= 1) ? (64 * 128) : 1];
    __shared__ float sacc[2][2 * CS];

    const int tid  = threadIdx.x;
    const int lane = tid & 63;
    const int wv   = tid >> 6;

    if constexpr (PHASE <= 2) {
        for (int j = tid; j < 2 * 2 * CS; j += 128) (&sacc[0][0])[j] = 0.f;
        __syncthreads();
    }

    const int r  = blockIdx.x * 128 + tid;
    const int i  = (int)idxf[r];
    const int bb = r >> 15;
    const int pp = (r >> 5) & 1023;

    float x[CIN0];
    {
        const float* pz = xyz + ((size_t)bb * NPTS + i) * 3;
        const float* nz = newxyz + ((size_t)bb * NPOINTS + pp) * 3;
        x[0] = pz[0] - nz[0];
        x[1] = pz[1] - nz[1];
        x[2] = pz[2] - nz[2];
        const float4* p4 = (const float4*)(points + ((size_t)bb * NPTS + i) * 64);
#pragma unroll
        for (int j = 0; j < 16; ++j) {
            const float4 v = p4[j];
            x[3+4*j+0] = v.x; x[3+4*j+1] = v.y; x[3+4*j+2] = v.z; x[3+4*j+3] = v.w;
        }
    }

#pragma unroll 1
    for (int oc = 0; oc < 16; ++oc) {
        const float4 bv = uld4(b0 + 4*oc);
        float a0 = bv.x, a1 = bv.y, a2 = bv.z, a3 = bv.w;
#pragma unroll
        for (int k = 0; k < CIN0; ++k) {
            const float4 w4 = uld4(W0 + k*64 + 4*oc);
            a0 = fmaf(x[k], w4.x, a0); a1 = fmaf(x[k], w4.y, a1);
            a2 = fmaf(x[k], w4.z, a2); a3 = fmaf(x[k], w4.w, a3);
        }
        if constexpr (PHASE == 0) {
            stats4(a0, a1, a2, a3, &sacc[wv][8*oc], lane);
        } else {
            xld[(4*oc+0)*128 + tid] = fmaxf(0.f, fmaf(a0, ss0[4*oc+0], ss0[64+4*oc+0]));
            xld[(4*oc+1)*128 + tid] = fmaxf(0.f, fmaf(a1, ss0[4*oc+1], ss0[64+4*oc+1]));
            xld[(4*oc+2)*128 + tid] = fmaxf(0.f, fmaf(a2, ss0[4*oc+2], ss0[64+4*oc+2]));
            xld[(4*oc+3)*128 + tid] = fmaxf(0.f, fmaf(a3, ss0[4*oc+3], ss0[64+4*oc+3]));
        }
    }

    if constexpr (PHASE == 1) {
#pragma unroll 1
        for (int oc = 0; oc < 16; ++oc) {
            const float4 bv = uld4(b1 + 4*oc);
            float a0 = bv.x, a1 = bv.y, a2 = bv.z, a3 = bv.w;
#pragma unroll
            for (int k = 0; k < 64; ++k) {
                const float xk = xld[k*128 + tid];
                const float4 w4 = uld4(W1 + k*64 + 4*oc);
                a0 = fmaf(xk, w4.x, a0); a1 = fmaf(xk, w4.y, a1);
                a2 = fmaf(xk, w4.z, a2); a3 = fmaf(xk, w4.w, a3);
            }
            stats4(a0, a1, a2, a3, &sacc[wv][8*oc], lane);
        }
    }

    if constexpr (PHASE >= 2) {
        float acc2[C2];
#pragma unroll
        for (int o = 0; o < C2; o += 4) {
            const float4 bv = uld4(b2 + o);
            acc2[o] = bv.x; acc2[o+1] = bv.y; acc2[o+2] = bv.z; acc2[o+3] = bv.w;
        }
#pragma unroll 1
        for (int oc = 0; oc < 16; ++oc) {
            const float4 bv = uld4(b1 + 4*oc);
            float a0 = bv.x, a1 = bv.y, a2 = bv.z, a3 = bv.w;
#pragma unroll
            for (int k = 0; k < 64; ++k) {
                const float xk = xld[k*128 + tid];
                const float4 w4 = uld4(W1 + k*64 + 4*oc);
                a0 = fmaf(xk, w4.x, a0); a1 = fmaf(xk, w4.y, a1);
                a2 = fmaf(xk, w4.z, a2); a3 = fmaf(xk, w4.w, a3);
            }
            const float xc0 = fmaxf(0.f, fmaf(a0, ss1[4*oc+0], ss1[64+4*oc+0]));
            const float xc1 = fmaxf(0.f, fmaf(a1, ss1[4*oc+1], ss1[64+4*oc+1]));
            const float xc2 = fmaxf(0.f, fmaf(a2, ss1[4*oc+2], ss1[64+4*oc+2]));
            const float xc3 = fmaxf(0.f, fmaf(a3, ss1[4*oc+3], ss1[64+4*oc+3]));
#pragma unroll
            for (int o = 0; o < C2; o += 4) {
                const float4 wA = uld4(W2 + (4*oc+0)*C2 + o);
                const float4 wB = uld4(W2 + (4*oc+1)*C2 + o);
                const float4 wC = uld4(W2 + (4*oc+2)*C2 + o);
                const float4 wD = uld4(W2 + (4*oc+3)*C2 + o);
                acc2[o+0] = fmaf(xc0, wA.x, fmaf(xc1, wB.x, fmaf(xc2, wC.x, fmaf(xc3, wD.x, acc2[o+0]))));
                acc2[o+1] = fmaf(xc0, wA.y, fmaf(xc1, wB.y, fmaf(xc2, wC.y, fmaf(xc3, wD.y, acc2[o+1]))));
                acc2[o+2] = fmaf(xc0, wA.z, fmaf(xc1, wB.z, fmaf(xc2, wC.z, fmaf(xc3, wD.z, acc2[o+2]))));
                acc2[o+3] = fmaf(xc0, wA.w, fmaf(xc1, wB.w, fmaf(xc2, wC.w, fmaf(xc3, wD.w, acc2[o+3]))));
            }
        }

        if constexpr (PHASE == 2) {
#pragma unroll
            for (int o = 0; o < C2; ++o) {
                const float s = dpp_sum64(acc2[o]);
                const float q = dpp_sum64(acc2[o] * acc2[o]);
                if (lane == 63) { sacc[wv][2*o] += s; sacc[wv][2*o+1] += q; }
            }
        } else {
            const int g = r >> 5;
#pragma unroll
            for (int o = 0; o < C2; ++o) {
                float v = fmaxf(0.f, fmaf(acc2[o], ss2[o], ss2[C2+o]));
                v = dpp_max32(v);
                if (lane == 31 || lane == 63) out_np[(size_t)g * C2 + o] = v;
            }
        }
    }

    if constexpr (PHASE <= 2) {
        __syncthreads();
        for (int j = tid; j < 2 * CS; j += 128)
            atomicAdd(&gstats[j], sacc[0][j] + sacc[1][j]);
    }
}

extern "C" void kernel_launch(void* const* d_in, const int* in_sizes, int n_in,
                              void* d_out, int out_size, void* d_ws, size_t ws_size,
                              hipStream_t stream)
{
    (void)in_sizes; (void)n_in; (void)out_size;
    const float* xyz    = (const float*)d_in[0];
    const float* points = (const float*)d_in[1];
    const float* W0  = (const float*)d_in[2];
    const float* b0  = (const float*)d_in[3];
    const float* g0  = (const float*)d_in[4];
    const float* be0 = (const float*)d_in[5];
    const float* W1  = (const float*)d_in[6];
    const float* b1  = (const float*)d_in[7];
    const float* g1  = (const float*)d_in[8];
    const float* be1 = (const float*)d_in[9];
    const float* W2  = (const float*)d_in[10];
    const float* b2  = (const float*)d_in[11];
    const float* g2  = (const float*)d_in[12];
    const float* be2 = (const float*)d_in[13];

    float* out = (float*)d_out;
    float* out_newxyz = out;                                    // 16*1024*3
    float* out_newpts = out + (size_t)NB * NPOINTS * 3;         // 16*1024*128
    float* out_idx    = out_newpts + (size_t)NB * NPOINTS * C2; // 16*1024*32 (float idx)

    float* wsf = (float*)d_ws;
    float* gs0 = wsf + 0;    // 128 (interleaved {s,q})
    float* gs1 = wsf + 128;  // 128
    float* gs2 = wsf + 256;  // 256
    float* ss0 = wsf + 512;  // 128 (fallback tiers)
    float* ss1 = wsf + 640;  // 128
    float* ss2 = wsf + 768;  // 256
    const size_t PBYTES  = (size_t)NB * NPTS * C0 * 4;            // 16 MB
    const size_t MMBYTES = (size_t)NB * NPOINTS * 2 * C2 * 4;     // 16 MB
    const size_t YBYTES  = MROWS * C1 * 2;                        // 64 MB (bf16)
    const size_t TBYTES  = (size_t)C2 * C1 * 2;                   // 16 KB (W2t)
    float* P    = (float*)((char*)d_ws + 65536);
    float* mnmx = (float*)((char*)d_ws + 65536 + PBYTES);
    unsigned short* y1b = (unsigned short*)((char*)d_ws + 65536 + PBYTES + MMBYTES);
    unsigned short* W2t = (unsigned short*)((char*)d_ws + 65536 + PBYTES + MMBYTES + YBYTES);

    const bool haveP = ws_size >= (65536 + PBYTES);
    const bool haveY = ws_size >= (65536 + PBYTES + MMBYTES + YBYTES + TBYTES);

    const int frontGrid = NB + 1 + (haveP ? (NB * NPTS / 512) : 0);
    fps_kernel<<<frontGrid, 512, 0, stream>>>(xyz, out_newxyz, wsf, points, W0, P,
                                              W2, haveY ? W2t : nullptr);

    if (haveY) {
        const int grid = (int)(MROWS / 256);  // 2048
        ballP0_kernel<<<grid, 256, 0, stream>>>(xyz, P, out_newxyz,
                                                W0, b0, gs0, out_idx);
        pass1Y_kernel<<<grid, 256, 0, stream>>>(xyz, P, out_newxyz, out_idx,
                                                W0, b0, W1, b1,
                                                gs0, g0, be0, gs1, y1b);
        p2Ym_kernel<<<(int)(MROWS / 128), 256, 0, stream>>>(y1b, W2t, b2,
                                                            gs1, g1, be1,
                                                            gs2, (float2*)mnmx);
        finY_kernel<<<NB * NPOINTS * C2 / 256, 256, 0, stream>>>((const float2*)mnmx,
                                                                 gs2, g2, be2, out_newpts);
    } else if (haveP) {
        ball_kernel<<<(NB * NPOINTS) / 4, 256, 0, stream>>>(xyz, out_newxyz, out_idx);
        const int grid = (int)(MROWS / 256);  // 2048
        preP_kernel<<<NB * NPTS / 256, 256, 0, stream>>>(points, W0, P);
        passP_kernel<0><<<grid, 256, 0, stream>>>(xyz, P, out_newxyz, out_idx,
                                                  W0, b0, W1, b1, W2, b2,
                                                  ss0, ss1, ss2, gs0, nullptr);
        ss_kernel<C0><<<1, C0, 0, stream>>>(gs0, g0, be0, ss0);
        passP_kernel<1><<<grid, 256, 0, stream>>>(xyz, P, out_newxyz, out_idx,
                                                  W0, b0, W1, b1, W2, b2,
                                                  ss0, ss1, ss2, gs1, nullptr);
        ss_kernel<C1><<<1, C1, 0, stream>>>(gs1, g1, be1, ss1);
        passP_kernel<2><<<grid, 256, 0, stream>>>(xyz, P, out_newxyz, out_idx,
                                                  W0, b0, W1, b1, W2, b2,
                                                  ss0, ss1, ss2, gs2, nullptr);
        ss_kernel<C2><<<1, C2, 0, stream>>>(gs2, g2, be2, ss2);
        passP_kernel<3><<<grid, 256, 0, stream>>>(xyz, P, out_newxyz, out_idx,
                                                  W0, b0, W1, b1, W2, b2,
                                                  ss0, ss1, ss2, nullptr, out_newpts);
    } else {
        ball_kernel<<<(NB * NPOINTS) / 4, 256, 0, stream>>>(xyz, out_newxyz, out_idx);
        const int grid = (int)(MROWS / 128);  // 4096
        pass_kernel<0><<<grid, 128, 0, stream>>>(xyz, points, out_newxyz, out_idx,
                                                 W0, b0, W1, b1, W2, b2,
                                                 ss0, ss1, ss2, gs0, nullptr);
        ss_kernel<C0><<<1, C0, 0, stream>>>(gs0, g0, be0, ss0);
        pass_kernel<1><<<grid, 128, 0, stream>>>(xyz, points, out_newxyz, out_idx,
                                                 W0, b0, W1, b1, W2, b2,
                                                 ss0, ss1, ss2, gs1, nullptr);
        ss_kernel<C1><<<1, C1, 0, stream>>>(gs1, g1, be1, ss1);
        pass_kernel<2><<<grid, 128, 0, stream>>>(xyz, points, out_newxyz, out_idx,
                                                 W0, b0, W1, b1, W2, b2,
                                                 ss0, ss1, ss2, gs2, nullptr);
        ss_kernel<C2><<<1, C2, 0, stream>>>(gs2, g2, be2, ss2);
        pass_kernel<3><<<grid, 128, 0, stream>>>(xyz, points, out_newxyz, out_idx,
                                                 W0, b0, W1, b1, W2, b2,
                                                 ss0, ss1, ss2, nullptr, out_newpts);
    }
}